// Round 1
// baseline (701.585 us; speedup 1.0000x reference)
//
#include <hip/hip_runtime.h>
#include <hip/hip_bf16.h>

#define NN 1024
#define HID 128
#define NHEADS 4
#define HDD 32
#define NL 3

// ---- ws layout (float-word units) ----
constexpr int OFF_FLAG = 0;      // ws[0]: 0.0f = fp32 inputs, 1.0f = bf16 inputs
constexpr int OFF_CONV = 16;
constexpr int OFF_NF   = OFF_CONV;            // 3072
constexpr int OFF_WP   = OFF_NF  + 3072;      // 384
constexpr int OFF_BP   = OFF_WP  + 384;       // 128
constexpr int OFF_WL   = OFF_BP  + 128;       // 49152
constexpr int OFF_WR   = OFF_WL  + 49152;     // 49152
constexpr int OFF_WVW  = OFF_WR  + 49152;     // 49152
constexpr int OFF_ATT  = OFF_WVW + 49152;     // 96
constexpr int OFF_GAM  = OFF_ATT + 96;        // 384
constexpr int OFF_BET  = OFF_GAM + 384;       // 384
constexpr int OFF_WN1  = OFF_BET + 384;       // 8192
constexpr int OFF_BN1  = OFF_WN1 + 8192;      // 64
constexpr int OFF_WN2  = OFF_BN1 + 64;        // 64
constexpr int OFF_BN2  = OFF_WN2 + 64;        // 1
constexpr int OFF_WD1  = OFF_BN2 + 1;         // 8192
constexpr int OFF_BD1  = OFF_WD1 + 8192;      // 64
constexpr int OFF_WD2  = OFF_BD1 + 64;        // 128
constexpr int OFF_BD2  = OFF_WD2 + 128;       // 2
constexpr int OFF_WV1  = OFF_BD2 + 2;         // 8192
constexpr int OFF_BV1  = OFF_WV1 + 8192;      // 64
constexpr int OFF_WV2  = OFF_BV1 + 64;        // 64
constexpr int OFF_BV2  = OFF_WV2 + 64;        // 1
constexpr int OFF_CONV_END = OFF_BV2 + 1;     // 176948
constexpr int CONV_TOTAL = OFF_CONV_END - OFF_CONV;  // 176932
constexpr int OFF_MASK = 176960;              // 1024*32 uint32 words
constexpr int OFF_H    = OFF_MASK + NN*32;    // 131072
constexpr int OFF_WLH  = OFF_H   + NN*HID;
constexpr int OFF_WRH  = OFF_WLH + NN*HID;
constexpr int OFF_WVH  = OFF_WRH + NN*HID;

__device__ __forceinline__ float bf2f(unsigned short u) {
    return __uint_as_float(((unsigned)u) << 16);
}
__device__ __forceinline__ void store_out(void* out, int idx, float v, bool bf) {
    if (bf) {
        unsigned u = __float_as_uint(v);
        unsigned r = (u + 0x7FFFu + ((u >> 16) & 1u)) >> 16;
        ((unsigned short*)out)[idx] = (unsigned short)r;
    } else {
        ((float*)out)[idx] = v;
    }
}

// ---- kernel 0: dtype detection ----
// fp32 normals: exponent field in [110,140] essentially always.
// packed bf16 pairs read as fp32: exponent field = (bf_exp<<1)|man_bit -> ~never in [110,140].
__global__ void k_detect(const unsigned* nf, float* ws) {
    unsigned w = nf[threadIdx.x];
    int e = (int)((w >> 23) & 0xFFu);
    unsigned long long b = __ballot(e >= 110 && e <= 140);
    if (threadIdx.x == 0) ws[0] = (__popcll(b) >= 32) ? 0.0f : 1.0f;
}

// ---- kernel 1: convert all non-adj params to fp32 in ws ----
struct P21 { const void* p[21]; };
__device__ const int g_sizes[21] = {3072,384,128,49152,49152,49152,96,384,384,
                                    8192,64,64,1,8192,64,128,2,8192,64,64,1};
__device__ const int g_dsts[21] = {OFF_NF,OFF_WP,OFF_BP,OFF_WL,OFF_WR,OFF_WVW,OFF_ATT,
                                   OFF_GAM,OFF_BET,OFF_WN1,OFF_BN1,OFF_WN2,OFF_BN2,
                                   OFF_WD1,OFF_BD1,OFF_WD2,OFF_BD2,OFF_WV1,OFF_BV1,
                                   OFF_WV2,OFF_BV2};
__global__ void k_convert(P21 in, float* ws) {
    bool bf = ws[0] > 0.5f;
    int g = blockIdx.x * blockDim.x + threadIdx.x;
    if (g >= CONV_TOTAL) return;
    int rem = g, s = 0;
    while (s < 21 && rem >= g_sizes[s]) { rem -= g_sizes[s]; s++; }
    if (s >= 21) return;
    float v;
    if (bf) v = bf2f(((const unsigned short*)in.p[s])[rem]);
    else    v = ((const float*)in.p[s])[rem];
    ws[g_dsts[s] + rem] = v;
}

// ---- kernel 2: adj -> packed bitmask ----
__global__ __launch_bounds__(1024) void k_mask(const void* adj, float* ws) {
    bool bf = ws[0] > 0.5f;
    unsigned* mask = (unsigned*)(ws + OFF_MASK);
    int i = blockIdx.x, t = threadIdx.x;
    float v = bf ? bf2f(((const unsigned short*)adj)[i * NN + t])
                 : ((const float*)adj)[i * NN + t];
    unsigned long long b = __ballot(v > 0.5f);
    int lane = t & 63, wv = t >> 6;
    if (lane == 0) {
        mask[i * 32 + wv * 2]     = (unsigned)b;
        mask[i * 32 + wv * 2 + 1] = (unsigned)(b >> 32);
    }
}

// ---- kernel 3: h0 = relu(nf @ Wp + bp) ----
__global__ __launch_bounds__(128) void k_h0(float* ws) {
    int i = blockIdx.x, c = threadIdx.x;
    const float* nf = ws + OFF_NF;
    const float* Wp = ws + OFF_WP;
    float a = ws[OFF_BP + c];
    #pragma unroll
    for (int k = 0; k < 3; k++) a += nf[i * 3 + k] * Wp[k * HID + c];
    ws[OFF_H + i * HID + c] = fmaxf(a, 0.0f);
}

// ---- kernel 4 (per layer): wlh/wrh/wv = h @ {Wl,Wr,Wv} ----
__global__ __launch_bounds__(128) void k_mm3(float* ws, int l) {
    __shared__ float hs[4][HID];
    int c = threadIdx.x, i0 = blockIdx.x * 4;
    const float* h = ws + OFF_H;
    #pragma unroll
    for (int r = 0; r < 4; r++) hs[r][c] = h[(i0 + r) * HID + c];
    __syncthreads();
    const float* Wl = ws + OFF_WL  + l * HID * HID;
    const float* Wr = ws + OFF_WR  + l * HID * HID;
    const float* Wv = ws + OFF_WVW + l * HID * HID;
    float al[4] = {0,0,0,0}, ar[4] = {0,0,0,0}, av[4] = {0,0,0,0};
    for (int k = 0; k < HID; k++) {
        float wl = Wl[k * HID + c], wr = Wr[k * HID + c], wv = Wv[k * HID + c];
        #pragma unroll
        for (int r = 0; r < 4; r++) {
            float hk = hs[r][k];
            al[r] += hk * wl; ar[r] += hk * wr; av[r] += hk * wv;
        }
    }
    #pragma unroll
    for (int r = 0; r < 4; r++) {
        ws[OFF_WLH + (i0 + r) * HID + c] = al[r];
        ws[OFF_WRH + (i0 + r) * HID + c] = ar[r];
        ws[OFF_WVH + (i0 + r) * HID + c] = av[r];
    }
}

// ---- kernel 5 (per layer): fused masked attention + softmax + agg + LN + residual ----
// block = 128 threads: t -> head = t>>5, d = t&31; one block per node i.
__global__ __launch_bounds__(128) void k_attn(float* ws, int l) {
    int i = blockIdx.x, t = threadIdx.x;
    __shared__ unsigned mrow[32];
    __shared__ float red[4];
    const unsigned* mask = (const unsigned*)(ws + OFF_MASK);
    if (t < 32) mrow[t] = mask[i * 32 + t];
    __syncthreads();

    float wl   = ws[OFF_WLH + i * HID + t];
    float attd = ws[OFF_ATT + l * HDD + (t & 31)];
    const float* wrh = ws + OFF_WRH;
    const float* wvh = ws + OFF_WVH;

    float m = -1e30f, lsum = 0.0f, acc = 0.0f;
    for (int jw = 0; jw < 32; jw++) {
        unsigned w = mrow[jw];
        while (w) {
            int b = __ffs(w) - 1; w &= (w - 1);
            int j = jw * 32 + b;
            float x = wl + wrh[j * HID + t];
            x = (x > 0.0f) ? x : 0.2f * x;          // leaky_relu(.,0.2)
            float p = attd * x;
            #pragma unroll
            for (int off = 16; off > 0; off >>= 1) p += __shfl_xor(p, off, 32);
            // p == e[i,j,head], identical across the 32-lane head group
            float mn = fmaxf(m, p);
            float sc = __expf(m - mn);
            float pe = __expf(p - mn);
            lsum = lsum * sc + pe;
            acc  = acc  * sc + pe * wvh[j * HID + t];
            m = mn;
        }
    }
    float agg = acc / lsum;

    // layernorm over 128 features
    float s = agg, s2 = agg * agg;
    #pragma unroll
    for (int off = 32; off > 0; off >>= 1) {
        s  += __shfl_xor(s,  off, 64);
        s2 += __shfl_xor(s2, off, 64);
    }
    int wv_ = t >> 6, lane = t & 63;
    if (lane == 0) { red[wv_ * 2] = s; red[wv_ * 2 + 1] = s2; }
    __syncthreads();
    float ts = red[0] + red[2], ts2 = red[1] + red[3];
    float mu  = ts  * (1.0f / HID);
    float var = ts2 * (1.0f / HID) - mu * mu;
    float g  = ws[OFF_GAM + l * HID + t];
    float be = ws[OFF_BET + l * HID + t];
    float o = (agg - mu) * rsqrtf(var + 1e-5f) * g + be;
    o = fmaxf(o, 0.0f);
    ws[OFF_H + i * HID + t] += o;   // residual
}

// ---- kernel 6: node_logits + delta_mu heads ----
__global__ __launch_bounds__(64) void k_heads(float* ws, void* out) {
    int i = blockIdx.x, t = threadIdx.x;
    __shared__ float hrow[HID];
    hrow[t]      = ws[OFF_H + i * HID + t];
    hrow[t + 64] = ws[OFF_H + i * HID + t + 64];
    __syncthreads();
    const float* Wn1 = ws + OFF_WN1;
    const float* Wd1 = ws + OFF_WD1;
    float z1 = ws[OFF_BN1 + t], zd = ws[OFF_BD1 + t];
    for (int k = 0; k < HID; k++) {
        float hk = hrow[k];
        z1 += hk * Wn1[k * 64 + t];
        zd += hk * Wd1[k * 64 + t];
    }
    z1 = fmaxf(z1, 0.0f); zd = fmaxf(zd, 0.0f);
    float lg = z1 * ws[OFF_WN2 + t];
    float d0 = zd * ws[OFF_WD2 + t * 2 + 0];
    float d1 = zd * ws[OFF_WD2 + t * 2 + 1];
    #pragma unroll
    for (int off = 32; off > 0; off >>= 1) {
        lg += __shfl_xor(lg, off, 64);
        d0 += __shfl_xor(d0, off, 64);
        d1 += __shfl_xor(d1, off, 64);
    }
    if (t == 0) {
        bool bf = ws[0] > 0.5f;
        store_out(out, i,                 lg + ws[OFF_BN2],     bf);
        store_out(out, NN + i * 2 + 0,    d0 + ws[OFF_BD2 + 0], bf);
        store_out(out, NN + i * 2 + 1,    d1 + ws[OFF_BD2 + 1], bf);
    }
}

// ---- kernel 7: pooled mean + value head ----
__global__ __launch_bounds__(1024) void k_value(float* ws, void* out) {
    __shared__ float part[8 * HID];
    __shared__ float pooled[HID];
    int t = threadIdx.x;
    int g = t >> 7, c = t & 127;
    float s = 0.0f;
    for (int r = 0; r < 128; r++) s += ws[OFF_H + (g * 128 + r) * HID + c];
    part[g * HID + c] = s;
    __syncthreads();
    if (t < HID) {
        float p = 0.0f;
        #pragma unroll
        for (int gg = 0; gg < 8; gg++) p += part[gg * HID + t];
        pooled[t] = p * (1.0f / NN);
    }
    __syncthreads();
    if (t < 64) {
        float z = ws[OFF_BV1 + t];
        for (int k = 0; k < HID; k++) z += pooled[k] * ws[OFF_WV1 + k * 64 + t];
        z = fmaxf(z, 0.0f);
        float pv = z * ws[OFF_WV2 + t];
        #pragma unroll
        for (int off = 32; off > 0; off >>= 1) pv += __shfl_xor(pv, off, 64);
        if (t == 0) {
            bool bf = ws[0] > 0.5f;
            store_out(out, 3072, pv + ws[OFF_BV2], bf);
        }
    }
}

extern "C" void kernel_launch(void* const* d_in, const int* in_sizes, int n_in,
                              void* d_out, int out_size, void* d_ws, size_t ws_size,
                              hipStream_t stream) {
    float* ws = (float*)d_ws;

    k_detect<<<1, 64, 0, stream>>>((const unsigned*)d_in[0], ws);

    P21 ptrs;
    const int map[21] = {0,2,3,4,5,6,7,8,9,10,11,12,13,14,15,16,17,18,19,20,21};
    for (int s = 0; s < 21; s++) ptrs.p[s] = d_in[map[s]];
    k_convert<<<(CONV_TOTAL + 255) / 256, 256, 0, stream>>>(ptrs, ws);

    k_mask<<<NN, 1024, 0, stream>>>(d_in[1], ws);
    k_h0<<<NN, 128, 0, stream>>>(ws);

    for (int l = 0; l < NL; l++) {
        k_mm3<<<NN / 4, 128, 0, stream>>>(ws, l);
        k_attn<<<NN, 128, 0, stream>>>(ws, l);
    }

    k_heads<<<NN, 64, 0, stream>>>(ws, d_out);
    k_value<<<1, 1024, 0, stream>>>(ws, d_out);
}

// Round 3
// 357.759 us; speedup vs baseline: 1.9611x; 1.9611x over previous
//
#include <hip/hip_runtime.h>
#include <hip/hip_bf16.h>

#define NN 1024
#define HID 128
#define NHEADS 4
#define HDD 32
#define NL 3

// ---- ws layout (float-word units) ----
constexpr int OFF_CONV = 16;
constexpr int OFF_NF   = OFF_CONV;            // 3072
constexpr int OFF_WP   = OFF_NF  + 3072;      // 384
constexpr int OFF_BP   = OFF_WP  + 384;       // 128
constexpr int OFF_WL   = OFF_BP  + 128;       // 49152
constexpr int OFF_WR   = OFF_WL  + 49152;     // 49152
constexpr int OFF_WVW  = OFF_WR  + 49152;     // 49152
constexpr int OFF_ATT  = OFF_WVW + 49152;     // 96
constexpr int OFF_GAM  = OFF_ATT + 96;        // 384
constexpr int OFF_BET  = OFF_GAM + 384;       // 384
constexpr int OFF_WN1  = OFF_BET + 384;       // 8192
constexpr int OFF_BN1  = OFF_WN1 + 8192;      // 64
constexpr int OFF_WN2  = OFF_BN1 + 64;        // 64
constexpr int OFF_BN2  = OFF_WN2 + 64;        // 1
constexpr int OFF_WD1  = OFF_BN2 + 1;         // 8192
constexpr int OFF_BD1  = OFF_WD1 + 8192;      // 64
constexpr int OFF_WD2  = OFF_BD1 + 64;        // 128
constexpr int OFF_BD2  = OFF_WD2 + 128;       // 2
constexpr int OFF_WV1  = OFF_BD2 + 2;         // 8192
constexpr int OFF_BV1  = OFF_WV1 + 8192;      // 64
constexpr int OFF_WV2  = OFF_BV1 + 64;        // 64
constexpr int OFF_BV2  = OFF_WV2 + 64;        // 1
constexpr int OFF_CONV_END = OFF_BV2 + 1;
constexpr int CONV_TOTAL = OFF_CONV_END - OFF_CONV;
constexpr int OFF_MASK = 176960;              // 1024*32 uint32 words
constexpr int OFF_H    = OFF_MASK + NN*32;
constexpr int OFF_WLH  = OFF_H   + NN*HID;
constexpr int OFF_WRH  = OFF_WLH + NN*HID;
constexpr int OFF_WVH  = OFF_WRH + NN*HID;

__device__ __forceinline__ float bf2f(unsigned short u) {
    return __uint_as_float(((unsigned)u) << 16);
}
__device__ __forceinline__ void store_out(void* out, int idx, float v, bool bf) {
    if (bf) {
        unsigned u = __float_as_uint(v);
        unsigned r = (u + 0x7FFFu + ((u >> 16) & 1u)) >> 16;
        ((unsigned short*)out)[idx] = (unsigned short)r;
    } else {
        ((float*)out)[idx] = v;
    }
}
// per-wave dtype sniff: fp32 normals have exponent field in [110,140];
// packed bf16 pairs viewed as fp32 essentially never do. Call from ALL lanes.
__device__ __forceinline__ bool detect_bf(const unsigned* nf) {
    unsigned w = nf[threadIdx.x & 63];
    int e = (int)((w >> 23) & 0xFFu);
    unsigned long long b = __ballot(e >= 110 && e <= 140);
    return __popcll(b) < 32;
}

// ---- convert all non-adj params to fp32 in ws ----
struct P21 { const void* p[21]; };
__device__ const int g_sizes[21] = {3072,384,128,49152,49152,49152,96,384,384,
                                    8192,64,64,1,8192,64,128,2,8192,64,64,1};
__device__ const int g_dsts[21] = {OFF_NF,OFF_WP,OFF_BP,OFF_WL,OFF_WR,OFF_WVW,OFF_ATT,
                                   OFF_GAM,OFF_BET,OFF_WN1,OFF_BN1,OFF_WN2,OFF_BN2,
                                   OFF_WD1,OFF_BD1,OFF_WD2,OFF_BD2,OFF_WV1,OFF_BV1,
                                   OFF_WV2,OFF_BV2};
__global__ __launch_bounds__(256) void k_convert(P21 in, const unsigned* nf, float* ws) {
    bool bf = detect_bf(nf);
    int g = blockIdx.x * blockDim.x + threadIdx.x;
    if (g >= CONV_TOTAL) return;
    int rem = g, s = 0;
    while (s < 21 && rem >= g_sizes[s]) { rem -= g_sizes[s]; s++; }
    if (s >= 21) return;
    float v;
    if (bf) v = bf2f(((const unsigned short*)in.p[s])[rem]);
    else    v = ((const float*)in.p[s])[rem];
    ws[g_dsts[s] + rem] = v;
}

// ---- adj -> packed bitmask ----
__global__ __launch_bounds__(1024) void k_mask(const void* adj, const unsigned* nf, float* ws) {
    bool bf = detect_bf(nf);
    unsigned* mask = (unsigned*)(ws + OFF_MASK);
    int i = blockIdx.x, t = threadIdx.x;
    float v = bf ? bf2f(((const unsigned short*)adj)[i * NN + t])
                 : ((const float*)adj)[i * NN + t];
    unsigned long long b = __ballot(v > 0.5f);
    int lane = t & 63, wv = t >> 6;
    if (lane == 0) {
        mask[i * 32 + wv * 2]     = (unsigned)b;
        mask[i * 32 + wv * 2 + 1] = (unsigned)(b >> 32);
    }
}

// ---- h0 = relu(nf @ Wp + bp) ----
__global__ __launch_bounds__(128) void k_h0(float* ws) {
    int i = blockIdx.x, c = threadIdx.x;
    const float* nf = ws + OFF_NF;
    const float* Wp = ws + OFF_WP;
    float a = ws[OFF_BP + c];
    #pragma unroll
    for (int k = 0; k < 3; k++) a += nf[i * 3 + k] * Wp[k * HID + c];
    ws[OFF_H + i * HID + c] = fmaxf(a, 0.0f);
}

// ---- per layer: wlh/wrh/wv = h @ {Wl,Wr,Wv}, split over blockIdx.y ----
__global__ __launch_bounds__(128) void k_mm3(float* ws, int l) {
    __shared__ float hs[4][HID];
    int c = threadIdx.x, i0 = blockIdx.x * 4, which = blockIdx.y;
    const float* h = ws + OFF_H;
    #pragma unroll
    for (int r = 0; r < 4; r++) hs[r][c] = h[(i0 + r) * HID + c];
    __syncthreads();
    int woff = (which == 0) ? OFF_WL : (which == 1) ? OFF_WR : OFF_WVW;
    int doff = (which == 0) ? OFF_WLH : (which == 1) ? OFF_WRH : OFF_WVH;
    const float* W = ws + woff + l * HID * HID;
    float a[4] = {0,0,0,0};
    #pragma unroll 4
    for (int k = 0; k < HID; k++) {
        float w = W[k * HID + c];
        #pragma unroll
        for (int r = 0; r < 4; r++) a[r] += hs[r][k] * w;
    }
    #pragma unroll
    for (int r = 0; r < 4; r++) ws[doff + (i0 + r) * HID + c] = a[r];
}

// ---- per layer: fused attention, lane-per-j ----
// block = 256 threads = 4 waves; wave w = head w; one block per node i.
// Each lane owns j = jc*64+lane, computes e lane-locally (no cross-lane in inner loop).
__global__ __launch_bounds__(256) void k_attn(float* ws, int l) {
    int i = blockIdx.x, t = threadIdx.x;
    int lane = t & 63;
    int h = __builtin_amdgcn_readfirstlane(t >> 6);
    __shared__ unsigned mrow[32];
    __shared__ float agg_s[HID];
    __shared__ float red[4];
    const unsigned* mask = (const unsigned*)(ws + OFF_MASK);
    if (t < 32) mrow[t] = mask[i * 32 + t];
    __syncthreads();

    // wave-uniform vectors -> registers (addresses uniform: i, h, l)
    float att_r[32], wl_r[32];
    const float* attp = ws + OFF_ATT + l * HDD;
    const float* wlp  = ws + OFF_WLH + i * HID + h * HDD;
    #pragma unroll
    for (int d = 0; d < 32; d++) { att_r[d] = attp[d]; wl_r[d] = wlp[d]; }

    const float* wrb = ws + OFF_WRH + h * HDD;
    const float* wvb = ws + OFF_WVH + h * HDD;

    // phase 1: e_j per lane, track lane max
    float e[16];
    float m = -1e30f;
    #pragma unroll
    for (int jc = 0; jc < 16; jc++) {
        int j = jc * 64 + lane;
        unsigned w = mrow[jc * 2 + (lane >> 5)];
        bool act = (w >> (lane & 31)) & 1u;
        float ej = -1e30f;
        if (act) {
            const float* wr = wrb + j * HID;
            float dot = 0.0f;
            #pragma unroll
            for (int d = 0; d < 32; d += 4) {
                float4 v = *(const float4*)(wr + d);
                float x0 = wl_r[d+0] + v.x; x0 = (x0 > 0.f) ? x0 : 0.2f * x0;
                float x1 = wl_r[d+1] + v.y; x1 = (x1 > 0.f) ? x1 : 0.2f * x1;
                float x2 = wl_r[d+2] + v.z; x2 = (x2 > 0.f) ? x2 : 0.2f * x2;
                float x3 = wl_r[d+3] + v.w; x3 = (x3 > 0.f) ? x3 : 0.2f * x3;
                dot += att_r[d+0]*x0 + att_r[d+1]*x1 + att_r[d+2]*x2 + att_r[d+3]*x3;
            }
            ej = dot;
            m = fmaxf(m, ej);
        }
        e[jc] = ej;
    }
    #pragma unroll
    for (int off = 32; off > 0; off >>= 1) m = fmaxf(m, __shfl_xor(m, off, 64));

    // phase 2: pe = exp(e - m), accumulate pe * v into lane-local acc[32]
    float acc[32];
    #pragma unroll
    for (int d = 0; d < 32; d++) acc[d] = 0.0f;
    float lsum = 0.0f;
    #pragma unroll
    for (int jc = 0; jc < 16; jc++) {
        if (e[jc] > -1e29f) {
            int j = jc * 64 + lane;
            float pe = __expf(e[jc] - m);
            lsum += pe;
            const float* wv = wvb + j * HID;
            #pragma unroll
            for (int d = 0; d < 32; d += 4) {
                float4 v = *(const float4*)(wv + d);
                acc[d+0] += pe * v.x; acc[d+1] += pe * v.y;
                acc[d+2] += pe * v.z; acc[d+3] += pe * v.w;
            }
        }
    }
    // butterfly-merge lsum + acc across the wave
    #pragma unroll
    for (int off = 32; off > 0; off >>= 1) {
        lsum += __shfl_xor(lsum, off, 64);
        #pragma unroll
        for (int d = 0; d < 32; d++) acc[d] += __shfl_xor(acc[d], off, 64);
    }
    if (lane == 0) {
        float inv = 1.0f / lsum;
        #pragma unroll
        for (int d = 0; d < 32; d++) agg_s[h * HDD + d] = acc[d] * inv;
    }
    __syncthreads();

    // layernorm over 128 features + residual, threads 0..127
    float s = 0.f, s2 = 0.f, agg = 0.f;
    if (t < HID) {
        agg = agg_s[t];
        s = agg; s2 = agg * agg;
        #pragma unroll
        for (int off = 32; off > 0; off >>= 1) {
            s  += __shfl_xor(s,  off, 64);
            s2 += __shfl_xor(s2, off, 64);
        }
        if ((t & 63) == 0) { red[(t >> 6) * 2] = s; red[(t >> 6) * 2 + 1] = s2; }
    }
    __syncthreads();
    if (t < HID) {
        float ts = red[0] + red[2], ts2 = red[1] + red[3];
        float mu  = ts  * (1.0f / HID);
        float var = ts2 * (1.0f / HID) - mu * mu;
        float g  = ws[OFF_GAM + l * HID + t];
        float be = ws[OFF_BET + l * HID + t];
        float o = (agg - mu) * rsqrtf(var + 1e-5f) * g + be;
        ws[OFF_H + i * HID + t] += fmaxf(o, 0.0f);
    }
}

// ---- node_logits + delta_mu heads ----
__global__ __launch_bounds__(64) void k_heads(float* ws, const unsigned* nf, void* out) {
    bool bf = detect_bf(nf);
    int i = blockIdx.x, t = threadIdx.x;
    __shared__ float hrow[HID];
    hrow[t]      = ws[OFF_H + i * HID + t];
    hrow[t + 64] = ws[OFF_H + i * HID + t + 64];
    __syncthreads();
    const float* Wn1 = ws + OFF_WN1;
    const float* Wd1 = ws + OFF_WD1;
    float z1 = ws[OFF_BN1 + t], zd = ws[OFF_BD1 + t];
    #pragma unroll 4
    for (int k = 0; k < HID; k++) {
        float hk = hrow[k];
        z1 += hk * Wn1[k * 64 + t];
        zd += hk * Wd1[k * 64 + t];
    }
    z1 = fmaxf(z1, 0.0f); zd = fmaxf(zd, 0.0f);
    float lg = z1 * ws[OFF_WN2 + t];
    float d0 = zd * ws[OFF_WD2 + t * 2 + 0];
    float d1 = zd * ws[OFF_WD2 + t * 2 + 1];
    #pragma unroll
    for (int off = 32; off > 0; off >>= 1) {
        lg += __shfl_xor(lg, off, 64);
        d0 += __shfl_xor(d0, off, 64);
        d1 += __shfl_xor(d1, off, 64);
    }
    if (t == 0) {
        store_out(out, i,              lg + ws[OFF_BN2],     bf);
        store_out(out, NN + i * 2 + 0, d0 + ws[OFF_BD2 + 0], bf);
        store_out(out, NN + i * 2 + 1, d1 + ws[OFF_BD2 + 1], bf);
    }
}

// ---- pooled mean + value head ----
__global__ __launch_bounds__(1024) void k_value(float* ws, const unsigned* nf, void* out) {
    bool bf = detect_bf(nf);
    __shared__ float part[8 * HID];
    __shared__ float pooled[HID];
    int t = threadIdx.x;
    int g = t >> 7, c = t & 127;
    float s = 0.0f;
    for (int r = 0; r < 128; r++) s += ws[OFF_H + (g * 128 + r) * HID + c];
    part[g * HID + c] = s;
    __syncthreads();
    if (t < HID) {
        float p = 0.0f;
        #pragma unroll
        for (int gg = 0; gg < 8; gg++) p += part[gg * HID + t];
        pooled[t] = p * (1.0f / NN);
    }
    __syncthreads();
    if (t < 64) {
        float z = ws[OFF_BV1 + t];
        for (int k = 0; k < HID; k++) z += pooled[k] * ws[OFF_WV1 + k * 64 + t];
        z = fmaxf(z, 0.0f);
        float pv = z * ws[OFF_WV2 + t];
        #pragma unroll
        for (int off = 32; off > 0; off >>= 1) pv += __shfl_xor(pv, off, 64);
        if (t == 0) store_out(out, 3072, pv + ws[OFF_BV2], bf);
    }
}

extern "C" void kernel_launch(void* const* d_in, const int* in_sizes, int n_in,
                              void* d_out, int out_size, void* d_ws, size_t ws_size,
                              hipStream_t stream) {
    float* ws = (float*)d_ws;
    const unsigned* nf = (const unsigned*)d_in[0];

    P21 ptrs;
    const int map[21] = {0,2,3,4,5,6,7,8,9,10,11,12,13,14,15,16,17,18,19,20,21};
    for (int s = 0; s < 21; s++) ptrs.p[s] = d_in[map[s]];
    k_convert<<<(CONV_TOTAL + 255) / 256, 256, 0, stream>>>(ptrs, nf, ws);

    k_mask<<<NN, 1024, 0, stream>>>(d_in[1], nf, ws);
    k_h0<<<NN, 128, 0, stream>>>(ws);

    for (int l = 0; l < NL; l++) {
        k_mm3<<<dim3(NN / 4, 3), 128, 0, stream>>>(ws, l);
        k_attn<<<NN, 256, 0, stream>>>(ws, l);
    }

    k_heads<<<NN, 64, 0, stream>>>(ws, nf, d_out);
    k_value<<<1, 1024, 0, stream>>>(ws, nf, d_out);
}